// Round 1
// baseline (517.094 us; speedup 1.0000x reference)
//
#include <hip/hip_runtime.h>
#include <math.h>

// VQ-VAE quantize: z [8,4096,512] f32, embed_w [1024,512] f32
// out = concat(z_q [8,4096,512], diff [8,4096,512], ind [8,4096] as f32)

#define D_DIM   512
#define K_CODES 1024
#define N_TOK   32768

#define BM 64
#define BN 128
#define BK 16
#define TM 4
#define TN 8
// 256 threads = 16(tx) x 16(ty); thread tile TM x TN -> 64 x 128 block tile

// ---------------- e2 = ||e_k||^2 precompute -------------------------------
__global__ __launch_bounds__(256) void vq_e2_kernel(const float* __restrict__ ew,
                                                    float* __restrict__ e2) {
    const int w    = threadIdx.x >> 6;   // wave in block (0..3)
    const int lane = threadIdx.x & 63;
    const int c    = blockIdx.x * 4 + w; // code id, grid = 256
    const float* row = &ew[(size_t)c * D_DIM];
    float s = 0.0f;
#pragma unroll
    for (int i = 0; i < D_DIM / 64; ++i) {
        float v = row[lane + i * 64];
        s = fmaf(v, v, s);
    }
#pragma unroll
    for (int off = 32; off > 0; off >>= 1) s += __shfl_xor(s, off, 64);
    if (lane == 0) e2[c] = s;
}

// ---------------- argmin over codes (fp32 SGEMM-style) --------------------
__global__ __launch_bounds__(256) void vq_argmin_kernel(
    const float* __restrict__ z, const float* __restrict__ ew,
    const float* __restrict__ e2, float* __restrict__ indf) {
    __shared__ float As[BK][BM];    // [k][m]
    __shared__ float Bs[BK][BN];    // [k][n]
    __shared__ float rv[BM][16];
    __shared__ int   ri[BM][16];

    const int t  = threadIdx.x;
    const int tx = t & 15;
    const int ty = t >> 4;
    const int row0 = blockIdx.x * BM;

    float best[TM];
    int   bidx[TM];
#pragma unroll
    for (int i = 0; i < TM; ++i) { best[i] = INFINITY; bidx[i] = 0; }

    // staging decomposition
    const int am = t >> 2;        // 0..63 (row within tile)
    const int ak = (t & 3) << 2;  // 0,4,8,12
    const int bn = t >> 1;        // 0..127 (code within tile)
    const int bk = (t & 1) << 3;  // 0,8

    for (int n0 = 0; n0 < K_CODES; n0 += BN) {
        float acc[TM][TN];
#pragma unroll
        for (int i = 0; i < TM; ++i)
#pragma unroll
            for (int j = 0; j < TN; ++j) acc[i][j] = 0.0f;

        for (int k0 = 0; k0 < D_DIM; k0 += BK) {
            float4 a  = *(const float4*)&z[(size_t)(row0 + am) * D_DIM + k0 + ak];
            float4 b0 = *(const float4*)&ew[(size_t)(n0 + bn) * D_DIM + k0 + bk];
            float4 b1 = *(const float4*)&ew[(size_t)(n0 + bn) * D_DIM + k0 + bk + 4];
            As[ak + 0][am] = a.x;  As[ak + 1][am] = a.y;
            As[ak + 2][am] = a.z;  As[ak + 3][am] = a.w;
            Bs[bk + 0][bn] = b0.x; Bs[bk + 1][bn] = b0.y;
            Bs[bk + 2][bn] = b0.z; Bs[bk + 3][bn] = b0.w;
            Bs[bk + 4][bn] = b1.x; Bs[bk + 5][bn] = b1.y;
            Bs[bk + 6][bn] = b1.z; Bs[bk + 7][bn] = b1.w;
            __syncthreads();
#pragma unroll
            for (int k = 0; k < BK; ++k) {
                float av[TM], bv[TN];
                *(float4*)&av[0] = *(const float4*)&As[k][ty * TM];
                *(float4*)&bv[0] = *(const float4*)&Bs[k][tx * TN];
                *(float4*)&bv[4] = *(const float4*)&Bs[k][tx * TN + 4];
#pragma unroll
                for (int i = 0; i < TM; ++i)
#pragma unroll
                    for (int j = 0; j < TN; ++j)
                        acc[i][j] = fmaf(av[i], bv[j], acc[i][j]);
            }
            __syncthreads();
        }

        // epilogue for this code tile: score = ||e||^2 - 2*dot  (row-constant
        // ||z||^2 dropped; does not change argmin). Codes processed in
        // ascending order with strict '<' -> first-min semantics.
#pragma unroll
        for (int j = 0; j < TN; ++j) {
            const int n = n0 + tx * TN + j;
            const float e2n = e2[n];
#pragma unroll
            for (int i = 0; i < TM; ++i) {
                const float s = fmaf(-2.0f, acc[i][j], e2n);
                if (s < best[i]) { best[i] = s; bidx[i] = n; }
            }
        }
    }

    // cross-thread (tx) reduce per row, lexicographic (val, idx) for
    // global first-index tie-break.
#pragma unroll
    for (int i = 0; i < TM; ++i) {
        rv[ty * TM + i][tx] = best[i];
        ri[ty * TM + i][tx] = bidx[i];
    }
    __syncthreads();
    if (t < BM) {
        float bv = rv[t][0];
        int   bi = ri[t][0];
#pragma unroll
        for (int c = 1; c < 16; ++c) {
            float v = rv[t][c];
            int   ix = ri[t][c];
            if (v < bv || (v == bv && ix < bi)) { bv = v; bi = ix; }
        }
        indf[row0 + t] = (float)bi;
    }
}

// ---------------- outputs: z_q, diff --------------------------------------
__global__ __launch_bounds__(256) void vq_out_kernel(
    const float* __restrict__ z, const float* __restrict__ ew,
    const float* __restrict__ indf, float* __restrict__ zq,
    float* __restrict__ diff) {
    const int w    = threadIdx.x >> 6;  // wave 0..3
    const int lane = threadIdx.x & 63;
    const int row  = blockIdx.x * 4 + w;
    const int c    = (int)indf[row];

    const float4* z4 = (const float4*)&z[(size_t)row * D_DIM];
    const float4* e4 = (const float4*)&ew[(size_t)c * D_DIM];
    float4* q4 = (float4*)&zq[(size_t)row * D_DIM];
    float4* d4 = (float4*)&diff[(size_t)row * D_DIM];

#pragma unroll
    for (int v = 0; v < 2; ++v) {
        const int i = v * 64 + lane;   // 128 float4 per row
        const float4 zv = z4[i];
        const float4 ev = e4[i];
        float4 qv, dv;
        // match reference rounding: a = e - z; diff = 0.25*(a*a + a*a) = 0.5*(a*a);
        // z_q = z + a
        float ax = ev.x - zv.x, ay = ev.y - zv.y, az = ev.z - zv.z, aw = ev.w - zv.w;
        qv.x = zv.x + ax; qv.y = zv.y + ay; qv.z = zv.z + az; qv.w = zv.w + aw;
        dv.x = 0.5f * (ax * ax); dv.y = 0.5f * (ay * ay);
        dv.z = 0.5f * (az * az); dv.w = 0.5f * (aw * aw);
        q4[i] = qv;
        d4[i] = dv;
    }
}

extern "C" void kernel_launch(void* const* d_in, const int* in_sizes, int n_in,
                              void* d_out, int out_size, void* d_ws, size_t ws_size,
                              hipStream_t stream) {
    const float* z  = (const float*)d_in[0];   // 8*4096*512
    const float* ew = (const float*)d_in[1];   // 1024*512
    float* out  = (float*)d_out;
    float* zq   = out;
    float* diff = out + (size_t)N_TOK * D_DIM;
    float* indf = out + (size_t)2 * N_TOK * D_DIM;
    float* e2   = (float*)d_ws;                // 4 KiB scratch

    hipLaunchKernelGGL(vq_e2_kernel, dim3(K_CODES / 4), dim3(256), 0, stream, ew, e2);
    hipLaunchKernelGGL(vq_argmin_kernel, dim3(N_TOK / BM), dim3(256), 0, stream,
                       z, ew, e2, indf);
    hipLaunchKernelGGL(vq_out_kernel, dim3(N_TOK / 4), dim3(256), 0, stream,
                       z, ew, indf, zq, diff);
}